// Round 10
// baseline (696.613 us; speedup 1.0000x reference)
//
#include <hip/hip_runtime.h>
#include <stdint.h>

#define NCLASS 41
#define TLEN   1024
#define NBATCH 1024
// per-batch backpointer stride: (TLEN-1)*NCLASS = 41943, round to mult of 8
#define BP_STRIDE 41944
#define NTRANS (NCLASS * NCLASS)
#define NEGINF (-3.0e38f)

// Full-wave max + broadcast via DPP (row_shr 1/2/4/8, row_bcast 15/31).
__device__ __forceinline__ float wave_max_bcast(float x) {
    int xi = __float_as_int(x);
    int t;
    t = __builtin_amdgcn_update_dpp(xi, xi, 0x111, 0xf, 0xf, false);  // row_shr:1
    x = fmaxf(x, __int_as_float(t)); xi = __float_as_int(x);
    t = __builtin_amdgcn_update_dpp(xi, xi, 0x112, 0xf, 0xf, false);  // row_shr:2
    x = fmaxf(x, __int_as_float(t)); xi = __float_as_int(x);
    t = __builtin_amdgcn_update_dpp(xi, xi, 0x114, 0xf, 0xf, false);  // row_shr:4
    x = fmaxf(x, __int_as_float(t)); xi = __float_as_int(x);
    t = __builtin_amdgcn_update_dpp(xi, xi, 0x118, 0xf, 0xf, false);  // row_shr:8
    x = fmaxf(x, __int_as_float(t)); xi = __float_as_int(x);
    t = __builtin_amdgcn_update_dpp(xi, xi, 0x142, 0xf, 0xf, false);  // row_bcast:15
    x = fmaxf(x, __int_as_float(t)); xi = __float_as_int(x);
    t = __builtin_amdgcn_update_dpp(xi, xi, 0x143, 0xf, 0xf, false);  // row_bcast:31
    x = fmaxf(x, __int_as_float(t));
    return __int_as_float(__builtin_amdgcn_readlane(__float_as_int(x), 63));
}

#define RDLANE(v, l) __int_as_float(__builtin_amdgcn_readlane(__float_as_int(v), (l)))

// ---------------------------------------------------------------------------
// Viterbi forward, round-6 exact narrow window (thr = wave_max(score) - D,
// on-chain), 2-wide both-ends candidate peel with overlapped LDS reads,
// exact serial redo only for |S| >= 3 (~5%).
//
// FAKE=1 (diagnostic): transition-row LDS reads replaced by a computed fake
// (2 VALU) -> measures the step chain WITHOUT the LDS component. REPS=2
// makes it the slowest dispatch so rocprof top-5 exposes its duration; its
// bp writes are fully overwritten by the FAKE=0 kernel afterwards and it
// writes nothing else, so the final output is untouched/exact.
// ---------------------------------------------------------------------------
template<int FAKE, int REPS>
__global__ __launch_bounds__(64, 1) void crf_fwd_t(
    const float* __restrict__ x,        // [B, T, C]
    const float* __restrict__ start_t,  // [C]
    const float* __restrict__ end_t,    // [C]
    const float* __restrict__ trans,    // [C, C]
    uint8_t* __restrict__ bp,           // [B, BP_STRIDE]
    int* __restrict__ out)              // [B, T]
{
    __shared__ float tl[NTRANS + 32];

    const int b = blockIdx.x;
    const int j = threadIdx.x;
    const bool act = (j < NCLASS);
    const int jc = act ? j : (NCLASS - 1);

    // Stage trans into LDS; D = max - min (exact, from data)
    float mx = NEGINF, mn = 3.0e38f;
    for (int k = j; k < NTRANS; k += 64) {
        float v = trans[k];
        tl[k] = v;
        mx = fmaxf(mx, v);
        mn = fminf(mn, v);
    }
    __syncthreads();
    const float Dmax = wave_max_bcast(mx);
    const float Dmin = -wave_max_bcast(-mn);
    const float D = Dmax - Dmin;

    const float* xb = x + (size_t)b * TLEN * NCLASS;
    uint8_t* bpb = bp + (size_t)b * BP_STRIDE;

    for (int rep = 0; rep < REPS; ++rep) {
        float score = act ? (start_t[j] + xb[j]) : NEGINF;

        // Transition value for candidate row i (uniform i), lane column jc.
        auto tval = [&](int i) -> float {
            if constexpr (FAKE) return (float)i * 0.00097f;   // 2 VALU, no LDS
            else return tl[i * NCLASS + jc];                  // ds_read_b32
        };

        auto step = [&](float e, int t) {
            float em = act ? e : NEGINF;
            float M = wave_max_bcast(score);        // on-chain, exact window
            float thr = M - D;
            unsigned long long me = __ballot(score >= thr);
            int i1 = __ffsll(me) - 1;
            int i2 = 63 - __clzll(me);              // == i1 when |S| == 1
            unsigned long long m3 = me & ~((1ull << i1) | (1ull << i2));
            float s1 = RDLANE(score, i1);
            float s2 = RDLANE(score, i2);
            float t1 = tval(i1);                    // both reads issue
            float t2 = tval(i2);                    //   back-to-back
            float v1 = s1 + t1;
            float v2 = s2 + t2;
            bool c = v2 > v1;                       // i1 < i2: strict > keeps
            float best = c ? v2 : v1;               //   first-index semantics
            int bidx = c ? i2 : i1;
            if (__builtin_expect(m3 != 0, 0)) {     // |S| >= 3: exact serial
                best = NEGINF; bidx = 0;
                unsigned long long mm = me;
                while (mm) {
                    int ic = __ffsll(mm) - 1; mm &= mm - 1;
                    float sc = RDLANE(score, ic);
                    float vc = sc + tval(ic);
                    if (vc > best) { best = vc; bidx = ic; }
                }
            }
            bpb[(size_t)(t - 1) * NCLASS + jc] = (uint8_t)bidx;
            score = best + em;
        };

        // Rolling 4-deep emission prefetch (rows t=1..4)
        float e0 = xb[1 * NCLASS + jc];
        float e1 = xb[2 * NCLASS + jc];
        float e2 = xb[3 * NCLASS + jc];
        float e3 = xb[4 * NCLASS + jc];

        int t0 = 1;
        for (; t0 + 3 <= TLEN - 4; t0 += 4) {  // steps 1..1020
            int r0 = t0 + 4, r1 = t0 + 5, r2 = t0 + 6, r3 = t0 + 7;
            r0 = r0 > TLEN - 1 ? TLEN - 1 : r0;
            r1 = r1 > TLEN - 1 ? TLEN - 1 : r1;
            r2 = r2 > TLEN - 1 ? TLEN - 1 : r2;
            r3 = r3 > TLEN - 1 ? TLEN - 1 : r3;
            step(e0, t0 + 0); e0 = xb[(size_t)r0 * NCLASS + jc];
            step(e1, t0 + 1); e1 = xb[(size_t)r1 * NCLASS + jc];
            step(e2, t0 + 2); e2 = xb[(size_t)r2 * NCLASS + jc];
            step(e3, t0 + 3); e3 = xb[(size_t)r3 * NCLASS + jc];
        }
        // Tail steps 1021..1023
        step(e0, TLEN - 3);
        step(e1, TLEN - 2);
        step(e2, TLEN - 1);

        if constexpr (!FAKE) {
            // Final: add end transitions, argmax over lanes (first-index tie)
            float fs = act ? (score + end_t[j]) : NEGINF;
            int idx = j;
#pragma unroll
            for (int off = 32; off >= 1; off >>= 1) {
                float ov = __shfl_xor(fs, off);
                int oi = __shfl_xor(idx, off);
                if (ov > fs || (ov == fs && oi < idx)) { fs = ov; idx = oi; }
            }
            if (j == 0) out[(size_t)b * TLEN + (TLEN - 1)] = idx;
        } else {
            asm volatile("" :: "v"(score));  // keep last-step chain live
        }
    }
}

// ---------------------------------------------------------------------------
// Kernel B: backtracking (unchanged; measured cheap).
// ---------------------------------------------------------------------------
__global__ __launch_bounds__(1024) void crf_backtrack(
    const uint8_t* __restrict__ bp,
    int* __restrict__ out)
{
    __shared__ uint8_t bpl[BP_STRIDE];     // 41944 B
    __shared__ int maps[16][NCLASS];       // chunk boundary maps
    __shared__ int entry[16];              // true tag at each chunk end

    const int b = blockIdx.x;
    const int tid = threadIdx.x;
    const int w = tid >> 6;
    const int lane = tid & 63;

    {
        const uint32_t* src = (const uint32_t*)(bp + (size_t)b * BP_STRIDE);
        uint32_t* dst = (uint32_t*)bpl;
        for (int i = tid; i < BP_STRIDE / 4; i += 1024) dst[i] = src[i];
    }
    __syncthreads();

    const int cs = w * 64;
    const int ce = min(cs + 64, TLEN - 1);  // last chunk: 63 columns
    const int L = ce - cs;

    // Phase 1: hypothesis walk for all 41 entering tags (lane = hypothesis)
    {
        int xx = (lane < NCLASS) ? lane : 0;
        for (int t = ce; t > cs; --t)
            xx = bpl[(t - 1) * NCLASS + xx];
        if (lane < NCLASS) maps[w][lane] = xx;
    }
    __syncthreads();

    // Stitch chunk boundaries serially on one thread
    if (tid == 0) {
        int cur = out[(size_t)b * TLEN + (TLEN - 1)];  // tag @ T-1 from fwd
        for (int ww = 15; ww >= 0; --ww) {
            entry[ww] = cur;
            cur = maps[ww][cur];
        }
    }
    __syncthreads();

    // Phase 2: replay with true entering tag; lane l captures step l's tag
    {
        int xx = entry[w];
        int cap = 0;
        for (int k = 0; k < L; ++k) {
            xx = bpl[(ce - 1 - k) * NCLASS + xx];
            if (k == lane) cap = xx;
        }
        if (lane < L) out[(size_t)b * TLEN + (ce - 1 - lane)] = cap;
    }
}

// ---------------------------------------------------------------------------
extern "C" void kernel_launch(void* const* d_in, const int* in_sizes, int n_in,
                              void* d_out, int out_size, void* d_ws, size_t ws_size,
                              hipStream_t stream) {
    const float* x       = (const float*)d_in[0];
    const float* start_t = (const float*)d_in[1];
    const float* end_t   = (const float*)d_in[2];
    const float* trans   = (const float*)d_in[3];
    int* out = (int*)d_out;
    uint8_t* bp = (uint8_t*)d_ws;  // needs NBATCH * BP_STRIDE = ~42.9 MB

    // Diagnostic first (no-LDS chain, x2 repeat): its bp/score effects are
    // fully overwritten by the real forward below; output stays exact.
    crf_fwd_t<1, 2><<<NBATCH, 64, 0, stream>>>(x, start_t, end_t, trans, bp, out);
    // Real forward
    crf_fwd_t<0, 1><<<NBATCH, 64, 0, stream>>>(x, start_t, end_t, trans, bp, out);
    crf_backtrack<<<NBATCH, 1024, 0, stream>>>(bp, out);
}

// Round 11
// 261.003 us; speedup vs baseline: 2.6690x; 2.6690x over previous
//
#include <hip/hip_runtime.h>
#include <stdint.h>

#define NCLASS 41
#define TLEN   1024
#define NBATCH 1024
// per-batch backpointer stride: (TLEN-1)*NCLASS = 41943, round to mult of 8
#define BP_STRIDE 41944
#define NTRANS (NCLASS * NCLASS)
#define NEGINF (-3.0e38f)
#define MASK41 ((1ull << NCLASS) - 1)

// Full-wave max + broadcast via DPP (row_shr 1/2/4/8, row_bcast 15/31).
__device__ __forceinline__ float wave_max_bcast(float x) {
    int xi = __float_as_int(x);
    int t;
    t = __builtin_amdgcn_update_dpp(xi, xi, 0x111, 0xf, 0xf, false);  // row_shr:1
    x = fmaxf(x, __int_as_float(t)); xi = __float_as_int(x);
    t = __builtin_amdgcn_update_dpp(xi, xi, 0x112, 0xf, 0xf, false);  // row_shr:2
    x = fmaxf(x, __int_as_float(t)); xi = __float_as_int(x);
    t = __builtin_amdgcn_update_dpp(xi, xi, 0x114, 0xf, 0xf, false);  // row_shr:4
    x = fmaxf(x, __int_as_float(t)); xi = __float_as_int(x);
    t = __builtin_amdgcn_update_dpp(xi, xi, 0x118, 0xf, 0xf, false);  // row_shr:8
    x = fmaxf(x, __int_as_float(t)); xi = __float_as_int(x);
    t = __builtin_amdgcn_update_dpp(xi, xi, 0x142, 0xf, 0xf, false);  // row_bcast:15
    x = fmaxf(x, __int_as_float(t)); xi = __float_as_int(x);
    t = __builtin_amdgcn_update_dpp(xi, xi, 0x143, 0xf, 0xf, false);  // row_bcast:31
    x = fmaxf(x, __int_as_float(t));
    return __int_as_float(__builtin_amdgcn_readlane(__float_as_int(x), 63));
}

#define RDLANE(v, l) __int_as_float(__builtin_amdgcn_readlane(__float_as_int(v), (l)))

// ---------------------------------------------------------------------------
// Viterbi forward — instruction-diet build of the round-10 winner.
// Exact narrow window (thr = wave_max(score) - D, on-chain); 2-wide
// both-ends peel; 4-wide only on the cnt>=3 branch (~4%); serial only for
// cnt>=5 (~0.5%). All 64 lanes run as mirrors of lane 40 (jc-clamped
// loads); the single SALU mask (me &= MASK41) replaces the two per-step
// exec cndmasks. 32-bit offset addressing for emission loads & bp stores.
// Rationale (r10 diag): at 1 wave/SIMD the step cost ~ 8cy x instruction
// count; LDS latency is NOT on the critical path. So: fewer instructions.
// ---------------------------------------------------------------------------
__global__ __launch_bounds__(64, 1) void crf_forward(
    const float* __restrict__ x,        // [B, T, C]
    const float* __restrict__ start_t,  // [C]
    const float* __restrict__ end_t,    // [C]
    const float* __restrict__ trans,    // [C, C]
    uint8_t* __restrict__ bp,           // [B, BP_STRIDE]
    int* __restrict__ out)              // [B, T]
{
    __shared__ float tl[NTRANS + 32];   // trans rows; pad so reads never OOB

    const int b = blockIdx.x;
    const int j = threadIdx.x;
    const int jc = (j < NCLASS) ? j : (NCLASS - 1);  // mirror lanes 41..63

    // Stage trans into LDS; D = max - min (exact, from data)
    float mx = NEGINF, mn = 3.0e38f;
    for (int k = j; k < NTRANS; k += 64) {
        float v = trans[k];
        tl[k] = v;
        mx = fmaxf(mx, v);
        mn = fminf(mn, v);
    }
    __syncthreads();
    const float Dmax = wave_max_bcast(mx);
    const float Dmin = -wave_max_bcast(-mn);
    const float D = Dmax - Dmin;

    const float* xb = x + (size_t)b * TLEN * NCLASS;
    uint8_t* bpb = bp + (size_t)b * BP_STRIDE;

    // All lanes live: lanes 41-63 mirror lane 40 (same loads, same values).
    float score = start_t[jc] + xb[jc];
    float thr = wave_max_bcast(score) - D;   // exact window for step 1

    // One step. e = this step's emission (mirrored); boff = bp byte offset.
    auto step = [&](float e, int boff) {
        unsigned long long me =
            __ballot(score >= thr) & MASK41;         // drop mirror lanes
        int cnt = __popcll(me);
        int i1 = __ffsll(me) - 1;
        int i2 = 63 - __clzll(me);                    // == i1 when cnt == 1
        float s1 = RDLANE(score, i1);
        float s2 = RDLANE(score, i2);
        float t1 = tl[i1 * NCLASS + jc];
        float t2 = tl[i2 * NCLASS + jc];
        float v1 = s1 + t1;
        float v2 = s2 + t2;
        bool c = v2 > v1;                             // i1 < i2: strict > keeps
        float best = c ? v2 : v1;                     //   first-index semantics
        int bidx = c ? i2 : i1;
        if (__builtin_expect(cnt >= 3, 0)) {
            unsigned long long mr =
                me & ~((1ull << i1) | (1ull << i2));
            if (__builtin_expect(cnt <= 4, 1)) {
                // ascending merge order: i1 < i3 <= i4 < i2
                int i3 = __ffsll(mr) - 1;
                int i4 = 63 - __clzll(mr);            // == i3 when cnt == 3
                float s3 = RDLANE(score, i3);
                float s4 = RDLANE(score, i4);
                float v3 = s3 + tl[i3 * NCLASS + jc];
                float v4 = s4 + tl[i4 * NCLASS + jc];
                best = v1; bidx = i1;
                if (v3 > best) { best = v3; bidx = i3; }
                if (v4 > best) { best = v4; bidx = i4; }
                if (v2 > best) { best = v2; bidx = i2; }
            } else {                                  // cnt >= 5: exact serial
                best = NEGINF; bidx = 0;
                unsigned long long mm = me;
                while (mm) {
                    int ic = __ffsll(mm) - 1; mm &= mm - 1;
                    float sc = RDLANE(score, ic);
                    float vc = sc + tl[ic * NCLASS + jc];
                    if (vc > best) { best = vc; bidx = ic; }
                }
            }
        }
        bpb[boff] = (uint8_t)bidx;                    // all lanes; mirrors dup
        score = best + e;
        thr = wave_max_bcast(score) - D;              // exact window, on-chain
    };

    // Rolling 4-deep emission prefetch, 32-bit offsets (SGPR base + voffset).
    int eoff = 1 * NCLASS + jc;          // element offset of em row 1
    float e0 = xb[eoff];
    float e1 = xb[eoff + NCLASS];
    float e2 = xb[eoff + 2 * NCLASS];
    float e3 = xb[eoff + 3 * NCLASS];
    eoff += 4 * NCLASS;                  // -> row t0+4 while t0 is current
    int boff = jc;                       // bp offset for t = 1

    // Main loop: steps 1..1016 (reloads rows t0+4..t0+7 <= 1020: never OOB)
    int t0 = 1;
    for (; t0 + 7 <= TLEN - 4; t0 += 4) {
        step(e0, boff);              e0 = xb[eoff];
        step(e1, boff + NCLASS);     e1 = xb[eoff + NCLASS];
        step(e2, boff + 2 * NCLASS); e2 = xb[eoff + 2 * NCLASS];
        step(e3, boff + 3 * NCLASS); e3 = xb[eoff + 3 * NCLASS];
        eoff += 4 * NCLASS;
        boff += 4 * NCLASS;
    }
    // Tail: t0 == 1017; e0..e3 hold rows 1017..1020. Steps 1017..1020 with
    // reloads of rows 1021..1023 (no OOB), then steps 1021..1023.
    step(e0, boff);              e0 = xb[eoff];               // row 1021
    step(e1, boff + NCLASS);     e1 = xb[eoff + NCLASS];      // row 1022
    step(e2, boff + 2 * NCLASS); e2 = xb[eoff + 2 * NCLASS];  // row 1023
    step(e3, boff + 3 * NCLASS);
    boff += 4 * NCLASS;
    step(e0, boff);
    step(e1, boff + NCLASS);
    step(e2, boff + 2 * NCLASS);

    // Final: add end transitions, argmax over lanes (first-index on tie).
    // Mirror lanes tie with lane 40; lower index wins, so result < 41.
    float fs = score + end_t[jc];
    int idx = j;
#pragma unroll
    for (int off = 32; off >= 1; off >>= 1) {
        float ov = __shfl_xor(fs, off);
        int oi = __shfl_xor(idx, off);
        if (ov > fs || (ov == fs && oi < idx)) { fs = ov; idx = oi; }
    }
    if (j == 0) out[(size_t)b * TLEN + (TLEN - 1)] = idx;
}

// ---------------------------------------------------------------------------
// Kernel B: backtracking (unchanged; measured cheap).
// ---------------------------------------------------------------------------
__global__ __launch_bounds__(1024) void crf_backtrack(
    const uint8_t* __restrict__ bp,
    int* __restrict__ out)
{
    __shared__ uint8_t bpl[BP_STRIDE];     // 41944 B
    __shared__ int maps[16][NCLASS];       // chunk boundary maps
    __shared__ int entry[16];              // true tag at each chunk end

    const int b = blockIdx.x;
    const int tid = threadIdx.x;
    const int w = tid >> 6;
    const int lane = tid & 63;

    {
        const uint32_t* src = (const uint32_t*)(bp + (size_t)b * BP_STRIDE);
        uint32_t* dst = (uint32_t*)bpl;
        for (int i = tid; i < BP_STRIDE / 4; i += 1024) dst[i] = src[i];
    }
    __syncthreads();

    const int cs = w * 64;
    const int ce = min(cs + 64, TLEN - 1);  // last chunk: 63 columns
    const int L = ce - cs;

    // Phase 1: hypothesis walk for all 41 entering tags (lane = hypothesis)
    {
        int xx = (lane < NCLASS) ? lane : 0;
        for (int t = ce; t > cs; --t)
            xx = bpl[(t - 1) * NCLASS + xx];
        if (lane < NCLASS) maps[w][lane] = xx;
    }
    __syncthreads();

    // Stitch chunk boundaries serially on one thread
    if (tid == 0) {
        int cur = out[(size_t)b * TLEN + (TLEN - 1)];  // tag @ T-1 from fwd
        for (int ww = 15; ww >= 0; --ww) {
            entry[ww] = cur;
            cur = maps[ww][cur];
        }
    }
    __syncthreads();

    // Phase 2: replay with true entering tag; lane l captures step l's tag
    {
        int xx = entry[w];
        int cap = 0;
        for (int k = 0; k < L; ++k) {
            xx = bpl[(ce - 1 - k) * NCLASS + xx];
            if (k == lane) cap = xx;
        }
        if (lane < L) out[(size_t)b * TLEN + (ce - 1 - lane)] = cap;
    }
}

// ---------------------------------------------------------------------------
extern "C" void kernel_launch(void* const* d_in, const int* in_sizes, int n_in,
                              void* d_out, int out_size, void* d_ws, size_t ws_size,
                              hipStream_t stream) {
    const float* x       = (const float*)d_in[0];
    const float* start_t = (const float*)d_in[1];
    const float* end_t   = (const float*)d_in[2];
    const float* trans   = (const float*)d_in[3];
    int* out = (int*)d_out;
    uint8_t* bp = (uint8_t*)d_ws;  // needs NBATCH * BP_STRIDE = ~42.9 MB

    crf_forward<<<NBATCH, 64, 0, stream>>>(x, start_t, end_t, trans, bp, out);
    crf_backtrack<<<NBATCH, 1024, 0, stream>>>(bp, out);
}